// Round 5
// baseline (269.394 us; speedup 1.0000x reference)
//
#include <hip/hip_runtime.h>
#include <math.h>

#define BATCH 1024
#define SEQ   200
#define DIN   128
#define DOUT  128
#define PSTR  608    // partial-delta row stride (floats): 600 data + 8 pad

// ---- K0: transpose S (64 KB, one-time) so both S and S^T are coalesced ----
__global__ __launch_bounds__(256) void k_transpose(const float* __restrict__ S,
                                                   float* __restrict__ ST) {
    int idx = blockIdx.x * 256 + threadIdx.x;   // 0..16383
    int d = idx >> 7, e = idx & 127;
    ST[e * DIN + d] = S[d * DOUT + e];
}

// ---- K1: one routing iteration, low_new never materialized.
//      (W@A)@S == W@(A@S) ; (high@S^T)@A^T == high@(A@S)^T.
//      Round-5 fix: EXPLICIT register-batched loads everywhere (the round-4
//      compiler chose 40 VGPRs and serialized every load at ~900cy; wall time
//      was per-block latency). (256,4): cap 128 regs, working set ~85. ----
__global__ __launch_bounds__(256, 4) void k_iter(
    const float* __restrict__ A,         // [B][200][128] fp32
    const float* __restrict__ S,         // [128][128]
    const float* __restrict__ ST,        // [128][128] transposed
    const float* __restrict__ Bm,        // [3][200]
    const int* __restrict__ seq,         // [B]
    const float* __restrict__ acc0, const float* __restrict__ acc1,
    float* __restrict__ part,            // [1024][PSTR]
    float* __restrict__ out, int iter) {
    __shared__ float sW[SEQ * 4];          // [l][k], k<3 used (3.2 KB)
    __shared__ float pB[4][3][DIN];        // partials, reused across phases (6 KB)
    __shared__ float sWA[3][DIN];          // W @ A   (1.5 KB)
    __shared__ float sH[3][DIN];           // squash(WA @ S) (1.5 KB)
    __shared__ float sHS[3][DIN];          // high @ S^T (1.5 KB)

    const int t = threadIdx.x;
    const int lane = t & 63, w = t >> 6;
    const int b = blockIdx.x;
    const float* Ab = A + (size_t)b * (SEQ * DIN);
    const int n = seq[b];

    // (1) softmax over logits (waves 0..2, one k each); sW=0 for l>=n
    if (w < 3) {
        const int k = w;
        // batch the three logit streams (independent loads, then combine)
        float v0[4], v1[4], v2[4];
#pragma unroll
        for (int i = 0; i < 4; ++i) {
            int l = lane + 64 * i;
            bool inb = (l < SEQ);
            v0[i] = inb ? Bm[k * SEQ + l] : 0.f;
            v1[i] = (inb && iter >= 1) ? acc0[k * SEQ + l] : 0.f;
            v2[i] = (inb && iter >= 2) ? acc1[k * SEQ + l] : 0.f;
        }
        float vv[4], m = -INFINITY;
#pragma unroll
        for (int i = 0; i < 4; ++i) {
            int l = lane + 64 * i;
            float v = v0[i] + v1[i] + v2[i];
            vv[i] = (l < n) ? v : -INFINITY;   // l<n implies l<SEQ
            if (l < n) m = fmaxf(m, v);
        }
        for (int off = 32; off; off >>= 1) m = fmaxf(m, __shfl_xor(m, off, 64));
        float s = 0.f, pv[4];
#pragma unroll
        for (int i = 0; i < 4; ++i) {
            pv[i] = (vv[i] == -INFINITY) ? 0.f : expf(vv[i] - m);
            s += pv[i];
        }
        for (int off = 32; off; off >>= 1) s += __shfl_xor(s, off, 64);
        float rs = 1.f / s;
#pragma unroll
        for (int i = 0; i < 4; ++i) {
            int l = lane + 64 * i;
            if (l < SEQ) sW[l * 4 + k] = pv[i] * rs;
        }
    }
    __syncthreads();

    // (2) WA partials: wave w sums l in [50w,50w+50); lane covers d=2lane,2lane+1.
    //     Explicit 25-deep load batches (50 VGPRs in flight) -> 2 HBM round trips
    //     instead of 50 serialized ones.
    {
        const float2* a2 = (const float2*)Ab;    // row stride 64 float2
        float h00 = 0.f, h01 = 0.f, h10 = 0.f, h11 = 0.f, h20 = 0.f, h21 = 0.f;
        float2 va[25];
#pragma unroll
        for (int g = 0; g < 2; ++g) {
#pragma unroll
            for (int j = 0; j < 25; ++j)
                va[j] = a2[(size_t)(w * 50 + g * 25 + j) * 64 + lane];
#pragma unroll
            for (int j = 0; j < 25; ++j) {
                int l = w * 50 + g * 25 + j;
                float4 wv = *(const float4*)&sW[l * 4];   // wave-uniform broadcast
                h00 = fmaf(wv.x, va[j].x, h00); h01 = fmaf(wv.x, va[j].y, h01);
                h10 = fmaf(wv.y, va[j].x, h10); h11 = fmaf(wv.y, va[j].y, h11);
                h20 = fmaf(wv.z, va[j].x, h20); h21 = fmaf(wv.z, va[j].y, h21);
            }
        }
        pB[w][0][2 * lane] = h00; pB[w][0][2 * lane + 1] = h01;
        pB[w][1][2 * lane] = h10; pB[w][1][2 * lane + 1] = h11;
        pB[w][2][2 * lane] = h20; pB[w][2][2 * lane + 1] = h21;
    }
    __syncthreads();

    // (3a) reduce WA across waves
    if (t < DIN) {
#pragma unroll
        for (int k = 0; k < 3; ++k)
            sWA[k][t] = pB[0][k][t] + pB[1][k][t] + pB[2][k][t] + pB[3][k][t];
    }
    __syncthreads();

    // (3b) high_raw = WA @ S ; e = t&127, half hh of d-range.
    //      Explicit 16-deep load batches (S rows are L2-hot).
    {
        const int e = t & 127, hh = t >> 7;
        const float* Scol = S + e;
        float g0 = 0.f, g1 = 0.f, g2 = 0.f;
        float sv[16];
#pragma unroll
        for (int g = 0; g < 4; ++g) {
#pragma unroll
            for (int j = 0; j < 16; ++j)
                sv[j] = Scol[(hh * 64 + g * 16 + j) * DOUT];
#pragma unroll
            for (int j = 0; j < 16; ++j) {
                int d = hh * 64 + g * 16 + j;
                g0 = fmaf(sWA[0][d], sv[j], g0);
                g1 = fmaf(sWA[1][d], sv[j], g1);
                g2 = fmaf(sWA[2][d], sv[j], g2);
            }
        }
        pB[hh][0][e] = g0; pB[hh][1][e] = g1; pB[hh][2][e] = g2;
    }
    __syncthreads();

    // (3c) combine halves + squash (norm over k per (b,e)); write out on last iter
    if (t < DIN) {
        float g0 = pB[0][0][t] + pB[1][0][t];
        float g1 = pB[0][1][t] + pB[1][1][t];
        float g2 = pB[0][2][t] + pB[1][2][t];
        float sq = g0 * g0 + g1 * g1 + g2 * g2;
        float scale = sq / (1.f + sq) / sqrtf(sq + 1e-9f);
        g0 *= scale; g1 *= scale; g2 *= scale;
        if (iter == 2) {
            size_t o = (size_t)b * 3 * DOUT + t;
            out[o] = g0; out[o + DOUT] = g1; out[o + 2 * DOUT] = g2;
        } else {
            sH[0][t] = g0; sH[1][t] = g1; sH[2][t] = g2;
        }
    }
    if (iter == 2) return;   // uniform exit
    __syncthreads();

    // (4a) hS = high @ S^T ; d = t&127, half hh of e-range. 16-deep batches.
    {
        const int d = t & 127, hh = t >> 7;
        const float* STcol = ST + d;
        float s0 = 0.f, s1 = 0.f, s2 = 0.f;
        float sv[16];
#pragma unroll
        for (int g = 0; g < 4; ++g) {
#pragma unroll
            for (int j = 0; j < 16; ++j)
                sv[j] = STcol[(hh * 64 + g * 16 + j) * DIN];
#pragma unroll
            for (int j = 0; j < 16; ++j) {
                int e = hh * 64 + g * 16 + j;
                s0 = fmaf(sH[0][e], sv[j], s0);
                s1 = fmaf(sH[1][e], sv[j], s1);
                s2 = fmaf(sH[2][e], sv[j], s2);
            }
        }
        pB[hh][0][d] = s0; pB[hh][1][d] = s1; pB[hh][2][d] = s2;
    }
    __syncthreads();

    if (t < DIN) {
#pragma unroll
        for (int k = 0; k < 3; ++k)
            sHS[k][t] = pB[0][k][t] + pB[1][k][t];
    }
    __syncthreads();

    // (5) B_delta partials: thread = l reads its 512B A-row; explicit 8-deep
    //     float4 batches (32 VGPRs in flight).
    if (t < SEQ) {
        const float* row = Ab + (size_t)t * DIN;
        float d0 = 0.f, d1 = 0.f, d2 = 0.f;
        float4 u[8];
#pragma unroll
        for (int g = 0; g < 4; ++g) {
#pragma unroll
            for (int j = 0; j < 8; ++j)
                u[j] = *(const float4*)&row[4 * (g * 8 + j)];
#pragma unroll
            for (int j = 0; j < 8; ++j) {
                int jj = g * 8 + j;
                float4 x0 = *(const float4*)&sHS[0][4 * jj];
                float4 x1 = *(const float4*)&sHS[1][4 * jj];
                float4 x2 = *(const float4*)&sHS[2][4 * jj];
                d0 += x0.x * u[j].x + x0.y * u[j].y + x0.z * u[j].z + x0.w * u[j].w;
                d1 += x1.x * u[j].x + x1.y * u[j].y + x1.z * u[j].z + x1.w * u[j].w;
                d2 += x2.x * u[j].x + x2.y * u[j].y + x2.z * u[j].z + x2.w * u[j].w;
            }
        }
        float* pp = part + (size_t)b * PSTR;
        pp[t] = d0;
        pp[SEQ + t] = d1;
        pp[2 * SEQ + t] = d2;
    }
}

// ---- K3: column-sum part[1024][PSTR] -> accN[600]; 150 blocks x 4 cols ----
__global__ __launch_bounds__(256, 4) void k_reduce(const float* __restrict__ part,
                                                   float* __restrict__ accN) {
    __shared__ float sP[4][4];
    const int t = threadIdx.x, lane = t & 63, w = t >> 6;
    const int c4 = blockIdx.x * 4;
    float4 v[4];
#pragma unroll
    for (int i = 0; i < 4; ++i)
        v[i] = *(const float4*)&part[(size_t)(t + 256 * i) * PSTR + c4];
    float sx = 0.f, sy = 0.f, sz = 0.f, sw = 0.f;
#pragma unroll
    for (int i = 0; i < 4; ++i) {
        sx += v[i].x; sy += v[i].y; sz += v[i].z; sw += v[i].w;
    }
#pragma unroll
    for (int off = 1; off < 64; off <<= 1) {
        sx += __shfl_xor(sx, off, 64);
        sy += __shfl_xor(sy, off, 64);
        sz += __shfl_xor(sz, off, 64);
        sw += __shfl_xor(sw, off, 64);
    }
    if (lane == 0) { sP[w][0] = sx; sP[w][1] = sy; sP[w][2] = sz; sP[w][3] = sw; }
    __syncthreads();
    if (t < 4)
        accN[c4 + t] = sP[0][t] + sP[1][t] + sP[2][t] + sP[3][t];
}

extern "C" void kernel_launch(void* const* d_in, const int* in_sizes, int n_in,
                              void* d_out, int out_size, void* d_ws, size_t ws_size,
                              hipStream_t stream) {
    const float* low_capsule = (const float*)d_in[0];   // [1024][200][128]
    const float* B_matrix    = (const float*)d_in[1];   // [1][3][200]
    const float* S_matrix    = (const float*)d_in[2];   // [128][128]
    const int*   seq_len     = (const int*)d_in[3];     // [1024]
    float* out = (float*)d_out;                         // [1024][3][128]

    float* ST   = (float*)d_ws;          // 16384
    float* acc0 = ST + 16384;            // 600 (+pad)
    float* acc1 = acc0 + 640;            // 600 (+pad)
    float* part = acc1 + 640;            // 1024 * PSTR

    k_transpose<<<64, 256, 0, stream>>>(S_matrix, ST);

    k_iter<<<BATCH, 256, 0, stream>>>(low_capsule, S_matrix, ST, B_matrix,
                                      seq_len, acc0, acc1, part, out, 0);
    k_reduce<<<150, 256, 0, stream>>>(part, acc0);
    k_iter<<<BATCH, 256, 0, stream>>>(low_capsule, S_matrix, ST, B_matrix,
                                      seq_len, acc0, acc1, part, out, 1);
    k_reduce<<<150, 256, 0, stream>>>(part, acc1);
    k_iter<<<BATCH, 256, 0, stream>>>(low_capsule, S_matrix, ST, B_matrix,
                                      seq_len, acc0, acc1, part, out, 2);
}

// Round 6
// 265.659 us; speedup vs baseline: 1.0141x; 1.0141x over previous
//
#include <hip/hip_runtime.h>
#include <math.h>

#define BATCH 1024
#define SEQ   200
#define DIN   128
#define DOUT  128
#define PSTR  608    // partial-delta row stride (floats): 600 data + 8 pad

// ---- K0: transpose S (64 KB, one-time) so both S and S^T are coalesced ----
__global__ __launch_bounds__(256) void k_transpose(const float* __restrict__ S,
                                                   float* __restrict__ ST) {
    int idx = blockIdx.x * 256 + threadIdx.x;   // 0..16383
    int d = idx >> 7, e = idx & 127;
    ST[e * DIN + d] = S[d * DOUT + e];
}

// ---- K1: one routing iteration, low_new never materialized.
//      (W@A)@S == W@(A@S) ; (high@S^T)@A^T == high@(A@S)^T.
//      Round-6 fix: NAMED-SCALAR 8-deep load batches (round 5's arrays were
//      spilled to scratch by the compiler: WRITE 2.4->30MB, dur 64->85us).
//      Named SSA scalars in short blocks keep peak pressure ~32 regs above
//      baseline and are not array-spill candidates. Order of all summations
//      identical to rounds 4/5 (bit-identical output). ----
__global__ __launch_bounds__(256, 4) void k_iter(
    const float* __restrict__ A,         // [B][200][128] fp32
    const float* __restrict__ S,         // [128][128]
    const float* __restrict__ ST,        // [128][128] transposed
    const float* __restrict__ Bm,        // [3][200]
    const int* __restrict__ seq,         // [B]
    const float* __restrict__ acc0, const float* __restrict__ acc1,
    float* __restrict__ part,            // [1024][PSTR]
    float* __restrict__ out, int iter) {
    __shared__ float sW[SEQ * 4];          // [l][k], k<3 used (3.2 KB)
    __shared__ float pB[4][3][DIN];        // partials, reused across phases (6 KB)
    __shared__ float sWA[3][DIN];          // W @ A   (1.5 KB)
    __shared__ float sH[3][DIN];           // squash(WA @ S) (1.5 KB)
    __shared__ float sHS[3][DIN];          // high @ S^T (1.5 KB)

    const int t = threadIdx.x;
    const int lane = t & 63, w = t >> 6;
    const int b = blockIdx.x;
    const float* Ab = A + (size_t)b * (SEQ * DIN);
    const int n = seq[b];

    // (1) softmax over logits (waves 0..2, one k each); sW=0 for l>=n
    if (w < 3) {
        const int k = w;
        float v0[4], v1[4], v2[4];
#pragma unroll
        for (int i = 0; i < 4; ++i) {
            int l = lane + 64 * i;
            bool inb = (l < SEQ);
            v0[i] = inb ? Bm[k * SEQ + l] : 0.f;
            v1[i] = (inb && iter >= 1) ? acc0[k * SEQ + l] : 0.f;
            v2[i] = (inb && iter >= 2) ? acc1[k * SEQ + l] : 0.f;
        }
        float vv[4], m = -INFINITY;
#pragma unroll
        for (int i = 0; i < 4; ++i) {
            int l = lane + 64 * i;
            float v = v0[i] + v1[i] + v2[i];
            vv[i] = (l < n) ? v : -INFINITY;   // l<n implies l<SEQ
            if (l < n) m = fmaxf(m, v);
        }
        for (int off = 32; off; off >>= 1) m = fmaxf(m, __shfl_xor(m, off, 64));
        float s = 0.f, pv[4];
#pragma unroll
        for (int i = 0; i < 4; ++i) {
            pv[i] = (vv[i] == -INFINITY) ? 0.f : expf(vv[i] - m);
            s += pv[i];
        }
        for (int off = 32; off; off >>= 1) s += __shfl_xor(s, off, 64);
        float rs = 1.f / s;
#pragma unroll
        for (int i = 0; i < 4; ++i) {
            int l = lane + 64 * i;
            if (l < SEQ) sW[l * 4 + k] = pv[i] * rs;
        }
    }
    __syncthreads();

    // (2) WA partials: wave w sums l in [50w,50w+50); lane covers d=2lane,2lane+1.
    //     8-deep named-scalar batches: 6x8 + 2 remainder.
    {
        const float2* a2 = (const float2*)Ab;    // row stride 64 float2
        float h00 = 0.f, h01 = 0.f, h10 = 0.f, h11 = 0.f, h20 = 0.f, h21 = 0.f;
        const int l0 = w * 50;

#define PB_FMA(WV, V) \
        h00 = fmaf(WV.x, V.x, h00); h01 = fmaf(WV.x, V.y, h01); \
        h10 = fmaf(WV.y, V.x, h10); h11 = fmaf(WV.y, V.y, h11); \
        h20 = fmaf(WV.z, V.x, h20); h21 = fmaf(WV.z, V.y, h21);

        for (int g = 0; g < 6; ++g) {
            const int lb = l0 + g * 8;
            float2 v0 = a2[(size_t)(lb + 0) * 64 + lane];
            float2 v1 = a2[(size_t)(lb + 1) * 64 + lane];
            float2 v2 = a2[(size_t)(lb + 2) * 64 + lane];
            float2 v3 = a2[(size_t)(lb + 3) * 64 + lane];
            float2 v4 = a2[(size_t)(lb + 4) * 64 + lane];
            float2 v5 = a2[(size_t)(lb + 5) * 64 + lane];
            float2 v6 = a2[(size_t)(lb + 6) * 64 + lane];
            float2 v7 = a2[(size_t)(lb + 7) * 64 + lane];
            float4 w0 = *(const float4*)&sW[(lb + 0) * 4];
            float4 w1 = *(const float4*)&sW[(lb + 1) * 4];
            float4 w2 = *(const float4*)&sW[(lb + 2) * 4];
            float4 w3 = *(const float4*)&sW[(lb + 3) * 4];
            float4 w4 = *(const float4*)&sW[(lb + 4) * 4];
            float4 w5 = *(const float4*)&sW[(lb + 5) * 4];
            float4 w6 = *(const float4*)&sW[(lb + 6) * 4];
            float4 w7 = *(const float4*)&sW[(lb + 7) * 4];
            PB_FMA(w0, v0) PB_FMA(w1, v1) PB_FMA(w2, v2) PB_FMA(w3, v3)
            PB_FMA(w4, v4) PB_FMA(w5, v5) PB_FMA(w6, v6) PB_FMA(w7, v7)
        }
        {   // remainder: rows l0+48, l0+49
            const int lb = l0 + 48;
            float2 v0 = a2[(size_t)(lb + 0) * 64 + lane];
            float2 v1 = a2[(size_t)(lb + 1) * 64 + lane];
            float4 w0 = *(const float4*)&sW[(lb + 0) * 4];
            float4 w1 = *(const float4*)&sW[(lb + 1) * 4];
            PB_FMA(w0, v0) PB_FMA(w1, v1)
        }
#undef PB_FMA
        pB[w][0][2 * lane] = h00; pB[w][0][2 * lane + 1] = h01;
        pB[w][1][2 * lane] = h10; pB[w][1][2 * lane + 1] = h11;
        pB[w][2][2 * lane] = h20; pB[w][2][2 * lane + 1] = h21;
    }
    __syncthreads();

    // (3a) reduce WA across waves
    if (t < DIN) {
#pragma unroll
        for (int k = 0; k < 3; ++k)
            sWA[k][t] = pB[0][k][t] + pB[1][k][t] + pB[2][k][t] + pB[3][k][t];
    }
    __syncthreads();

    // (3b) high_raw = WA @ S ; e = t&127, half hh of d-range. 8x8 named batches.
    {
        const int e = t & 127, hh = t >> 7;
        const float* Scol = S + e;
        float g0 = 0.f, g1 = 0.f, g2 = 0.f;
        for (int g = 0; g < 8; ++g) {
            const int db = hh * 64 + g * 8;
            float s0 = Scol[(db + 0) * DOUT];
            float s1 = Scol[(db + 1) * DOUT];
            float s2 = Scol[(db + 2) * DOUT];
            float s3 = Scol[(db + 3) * DOUT];
            float s4 = Scol[(db + 4) * DOUT];
            float s5 = Scol[(db + 5) * DOUT];
            float s6 = Scol[(db + 6) * DOUT];
            float s7 = Scol[(db + 7) * DOUT];
#define HB_FMA(J, SV) \
            g0 = fmaf(sWA[0][db + J], SV, g0); \
            g1 = fmaf(sWA[1][db + J], SV, g1); \
            g2 = fmaf(sWA[2][db + J], SV, g2);
            HB_FMA(0, s0) HB_FMA(1, s1) HB_FMA(2, s2) HB_FMA(3, s3)
            HB_FMA(4, s4) HB_FMA(5, s5) HB_FMA(6, s6) HB_FMA(7, s7)
#undef HB_FMA
        }
        pB[hh][0][e] = g0; pB[hh][1][e] = g1; pB[hh][2][e] = g2;
    }
    __syncthreads();

    // (3c) combine halves + squash (norm over k per (b,e)); write out on last iter
    if (t < DIN) {
        float g0 = pB[0][0][t] + pB[1][0][t];
        float g1 = pB[0][1][t] + pB[1][1][t];
        float g2 = pB[0][2][t] + pB[1][2][t];
        float sq = g0 * g0 + g1 * g1 + g2 * g2;
        float scale = sq / (1.f + sq) / sqrtf(sq + 1e-9f);
        g0 *= scale; g1 *= scale; g2 *= scale;
        if (iter == 2) {
            size_t o = (size_t)b * 3 * DOUT + t;
            out[o] = g0; out[o + DOUT] = g1; out[o + 2 * DOUT] = g2;
        } else {
            sH[0][t] = g0; sH[1][t] = g1; sH[2][t] = g2;
        }
    }
    if (iter == 2) return;   // uniform exit
    __syncthreads();

    // (4a) hS = high @ S^T ; d = t&127, half hh of e-range. 8x8 named batches.
    {
        const int d = t & 127, hh = t >> 7;
        const float* STcol = ST + d;
        float s0a = 0.f, s1a = 0.f, s2a = 0.f;
        for (int g = 0; g < 8; ++g) {
            const int eb = hh * 64 + g * 8;
            float s0 = STcol[(eb + 0) * DIN];
            float s1 = STcol[(eb + 1) * DIN];
            float s2 = STcol[(eb + 2) * DIN];
            float s3 = STcol[(eb + 3) * DIN];
            float s4 = STcol[(eb + 4) * DIN];
            float s5 = STcol[(eb + 5) * DIN];
            float s6 = STcol[(eb + 6) * DIN];
            float s7 = STcol[(eb + 7) * DIN];
#define HS_FMA(J, SV) \
            s0a = fmaf(sH[0][eb + J], SV, s0a); \
            s1a = fmaf(sH[1][eb + J], SV, s1a); \
            s2a = fmaf(sH[2][eb + J], SV, s2a);
            HS_FMA(0, s0) HS_FMA(1, s1) HS_FMA(2, s2) HS_FMA(3, s3)
            HS_FMA(4, s4) HS_FMA(5, s5) HS_FMA(6, s6) HS_FMA(7, s7)
#undef HS_FMA
        }
        pB[hh][0][d] = s0a; pB[hh][1][d] = s1a; pB[hh][2][d] = s2a;
    }
    __syncthreads();

    if (t < DIN) {
#pragma unroll
        for (int k = 0; k < 3; ++k)
            sHS[k][t] = pB[0][k][t] + pB[1][k][t];
    }
    __syncthreads();

    // (5) B_delta partials: thread = l reads its 512B A-row; 4 groups of
    //     8-deep named float4 batches.
    if (t < SEQ) {
        const float* row = Ab + (size_t)t * DIN;
        float d0 = 0.f, d1 = 0.f, d2 = 0.f;
        for (int g = 0; g < 4; ++g) {
            const int jb = g * 8;
            float4 u0 = *(const float4*)&row[4 * (jb + 0)];
            float4 u1 = *(const float4*)&row[4 * (jb + 1)];
            float4 u2 = *(const float4*)&row[4 * (jb + 2)];
            float4 u3 = *(const float4*)&row[4 * (jb + 3)];
            float4 u4 = *(const float4*)&row[4 * (jb + 4)];
            float4 u5 = *(const float4*)&row[4 * (jb + 5)];
            float4 u6 = *(const float4*)&row[4 * (jb + 6)];
            float4 u7 = *(const float4*)&row[4 * (jb + 7)];
#define PC_FMA(J, U) { \
            float4 x0 = *(const float4*)&sHS[0][4 * (jb + J)]; \
            float4 x1 = *(const float4*)&sHS[1][4 * (jb + J)]; \
            float4 x2 = *(const float4*)&sHS[2][4 * (jb + J)]; \
            d0 += x0.x * U.x + x0.y * U.y + x0.z * U.z + x0.w * U.w; \
            d1 += x1.x * U.x + x1.y * U.y + x1.z * U.z + x1.w * U.w; \
            d2 += x2.x * U.x + x2.y * U.y + x2.z * U.z + x2.w * U.w; }
            PC_FMA(0, u0) PC_FMA(1, u1) PC_FMA(2, u2) PC_FMA(3, u3)
            PC_FMA(4, u4) PC_FMA(5, u5) PC_FMA(6, u6) PC_FMA(7, u7)
#undef PC_FMA
        }
        float* pp = part + (size_t)b * PSTR;
        pp[t] = d0;
        pp[SEQ + t] = d1;
        pp[2 * SEQ + t] = d2;
    }
}

// ---- K3: column-sum part[1024][PSTR] -> accN[600]; 150 blocks x 4 cols ----
__global__ __launch_bounds__(256, 4) void k_reduce(const float* __restrict__ part,
                                                   float* __restrict__ accN) {
    __shared__ float sP[4][4];
    const int t = threadIdx.x, lane = t & 63, w = t >> 6;
    const int c4 = blockIdx.x * 4;
    float4 v0 = *(const float4*)&part[(size_t)(t + 256 * 0) * PSTR + c4];
    float4 v1 = *(const float4*)&part[(size_t)(t + 256 * 1) * PSTR + c4];
    float4 v2 = *(const float4*)&part[(size_t)(t + 256 * 2) * PSTR + c4];
    float4 v3 = *(const float4*)&part[(size_t)(t + 256 * 3) * PSTR + c4];
    float sx = v0.x + v1.x + v2.x + v3.x;
    float sy = v0.y + v1.y + v2.y + v3.y;
    float sz = v0.z + v1.z + v2.z + v3.z;
    float sw = v0.w + v1.w + v2.w + v3.w;
#pragma unroll
    for (int off = 1; off < 64; off <<= 1) {
        sx += __shfl_xor(sx, off, 64);
        sy += __shfl_xor(sy, off, 64);
        sz += __shfl_xor(sz, off, 64);
        sw += __shfl_xor(sw, off, 64);
    }
    if (lane == 0) { sP[w][0] = sx; sP[w][1] = sy; sP[w][2] = sz; sP[w][3] = sw; }
    __syncthreads();
    if (t < 4)
        accN[c4 + t] = sP[0][t] + sP[1][t] + sP[2][t] + sP[3][t];
}

extern "C" void kernel_launch(void* const* d_in, const int* in_sizes, int n_in,
                              void* d_out, int out_size, void* d_ws, size_t ws_size,
                              hipStream_t stream) {
    const float* low_capsule = (const float*)d_in[0];   // [1024][200][128]
    const float* B_matrix    = (const float*)d_in[1];   // [1][3][200]
    const float* S_matrix    = (const float*)d_in[2];   // [128][128]
    const int*   seq_len     = (const int*)d_in[3];     // [1024]
    float* out = (float*)d_out;                         // [1024][3][128]

    float* ST   = (float*)d_ws;          // 16384
    float* acc0 = ST + 16384;            // 600 (+pad)
    float* acc1 = acc0 + 640;            // 600 (+pad)
    float* part = acc1 + 640;            // 1024 * PSTR

    k_transpose<<<64, 256, 0, stream>>>(S_matrix, ST);

    k_iter<<<BATCH, 256, 0, stream>>>(low_capsule, S_matrix, ST, B_matrix,
                                      seq_len, acc0, acc1, part, out, 0);
    k_reduce<<<150, 256, 0, stream>>>(part, acc0);
    k_iter<<<BATCH, 256, 0, stream>>>(low_capsule, S_matrix, ST, B_matrix,
                                      seq_len, acc0, acc1, part, out, 1);
    k_reduce<<<150, 256, 0, stream>>>(part, acc1);
    k_iter<<<BATCH, 256, 0, stream>>>(low_capsule, S_matrix, ST, B_matrix,
                                      seq_len, acc0, acc1, part, out, 2);
}

// Round 7
// 249.960 us; speedup vs baseline: 1.0777x; 1.0628x over previous
//
#include <hip/hip_runtime.h>
#include <math.h>

#define BATCH 1024
#define SEQ   200
#define DIN   128
#define DOUT  128
#define PSTR  608    // partial-delta row stride (floats): 600 data + 8 pad

// ---- K0: transpose S (64 KB, one-time) so both S and S^T are coalesced ----
__global__ __launch_bounds__(256) void k_transpose(const float* __restrict__ S,
                                                   float* __restrict__ ST) {
    int idx = blockIdx.x * 256 + threadIdx.x;   // 0..16383
    int d = idx >> 7, e = idx & 127;
    ST[e * DIN + d] = S[d * DOUT + e];
}

// ---- K1: one routing iteration, low_new never materialized.
//      (W@A)@S == W@(A@S) ; (high@S^T)@A^T == high@(A@S)^T.
//      Round-7: SAME code as round 6, launch_bounds (256,4)->(256,2).
//      (256,4) sets waves/EU range [4,8]; the allocator chased 8 waves/EU
//      (64 VGPR) and spilled ~25MB/dispatch (r5: WRITE 30MB; r6: 27MB).
//      (256,2) range [2,8] lets it settle ~112 regs (round-0 precedent),
//      keeping the 8-deep named load batches in registers: MLP=8. ----
__global__ __launch_bounds__(256, 2) void k_iter(
    const float* __restrict__ A,         // [B][200][128] fp32
    const float* __restrict__ S,         // [128][128]
    const float* __restrict__ ST,        // [128][128] transposed
    const float* __restrict__ Bm,        // [3][200]
    const int* __restrict__ seq,         // [B]
    const float* __restrict__ acc0, const float* __restrict__ acc1,
    float* __restrict__ part,            // [1024][PSTR]
    float* __restrict__ out, int iter) {
    __shared__ float sW[SEQ * 4];          // [l][k], k<3 used (3.2 KB)
    __shared__ float pB[4][3][DIN];        // partials, reused across phases (6 KB)
    __shared__ float sWA[3][DIN];          // W @ A   (1.5 KB)
    __shared__ float sH[3][DIN];           // squash(WA @ S) (1.5 KB)
    __shared__ float sHS[3][DIN];          // high @ S^T (1.5 KB)

    const int t = threadIdx.x;
    const int lane = t & 63, w = t >> 6;
    const int b = blockIdx.x;
    const float* Ab = A + (size_t)b * (SEQ * DIN);
    const int n = seq[b];

    // (1) softmax over logits (waves 0..2, one k each); sW=0 for l>=n
    if (w < 3) {
        const int k = w;
        float v0[4], v1[4], v2[4];
#pragma unroll
        for (int i = 0; i < 4; ++i) {
            int l = lane + 64 * i;
            bool inb = (l < SEQ);
            v0[i] = inb ? Bm[k * SEQ + l] : 0.f;
            v1[i] = (inb && iter >= 1) ? acc0[k * SEQ + l] : 0.f;
            v2[i] = (inb && iter >= 2) ? acc1[k * SEQ + l] : 0.f;
        }
        float vv[4], m = -INFINITY;
#pragma unroll
        for (int i = 0; i < 4; ++i) {
            int l = lane + 64 * i;
            float v = v0[i] + v1[i] + v2[i];
            vv[i] = (l < n) ? v : -INFINITY;   // l<n implies l<SEQ
            if (l < n) m = fmaxf(m, v);
        }
        for (int off = 32; off; off >>= 1) m = fmaxf(m, __shfl_xor(m, off, 64));
        float s = 0.f, pv[4];
#pragma unroll
        for (int i = 0; i < 4; ++i) {
            pv[i] = (vv[i] == -INFINITY) ? 0.f : expf(vv[i] - m);
            s += pv[i];
        }
        for (int off = 32; off; off >>= 1) s += __shfl_xor(s, off, 64);
        float rs = 1.f / s;
#pragma unroll
        for (int i = 0; i < 4; ++i) {
            int l = lane + 64 * i;
            if (l < SEQ) sW[l * 4 + k] = pv[i] * rs;
        }
    }
    __syncthreads();

    // (2) WA partials: wave w sums l in [50w,50w+50); lane covers d=2lane,2lane+1.
    //     8-deep named-scalar batches: 6x8 + 2 remainder.
    {
        const float2* a2 = (const float2*)Ab;    // row stride 64 float2
        float h00 = 0.f, h01 = 0.f, h10 = 0.f, h11 = 0.f, h20 = 0.f, h21 = 0.f;
        const int l0 = w * 50;

#define PB_FMA(WV, V) \
        h00 = fmaf(WV.x, V.x, h00); h01 = fmaf(WV.x, V.y, h01); \
        h10 = fmaf(WV.y, V.x, h10); h11 = fmaf(WV.y, V.y, h11); \
        h20 = fmaf(WV.z, V.x, h20); h21 = fmaf(WV.z, V.y, h21);

        for (int g = 0; g < 6; ++g) {
            const int lb = l0 + g * 8;
            float2 v0 = a2[(size_t)(lb + 0) * 64 + lane];
            float2 v1 = a2[(size_t)(lb + 1) * 64 + lane];
            float2 v2 = a2[(size_t)(lb + 2) * 64 + lane];
            float2 v3 = a2[(size_t)(lb + 3) * 64 + lane];
            float2 v4 = a2[(size_t)(lb + 4) * 64 + lane];
            float2 v5 = a2[(size_t)(lb + 5) * 64 + lane];
            float2 v6 = a2[(size_t)(lb + 6) * 64 + lane];
            float2 v7 = a2[(size_t)(lb + 7) * 64 + lane];
            float4 w0 = *(const float4*)&sW[(lb + 0) * 4];
            float4 w1 = *(const float4*)&sW[(lb + 1) * 4];
            float4 w2 = *(const float4*)&sW[(lb + 2) * 4];
            float4 w3 = *(const float4*)&sW[(lb + 3) * 4];
            float4 w4 = *(const float4*)&sW[(lb + 4) * 4];
            float4 w5 = *(const float4*)&sW[(lb + 5) * 4];
            float4 w6 = *(const float4*)&sW[(lb + 6) * 4];
            float4 w7 = *(const float4*)&sW[(lb + 7) * 4];
            PB_FMA(w0, v0) PB_FMA(w1, v1) PB_FMA(w2, v2) PB_FMA(w3, v3)
            PB_FMA(w4, v4) PB_FMA(w5, v5) PB_FMA(w6, v6) PB_FMA(w7, v7)
        }
        {   // remainder: rows l0+48, l0+49
            const int lb = l0 + 48;
            float2 v0 = a2[(size_t)(lb + 0) * 64 + lane];
            float2 v1 = a2[(size_t)(lb + 1) * 64 + lane];
            float4 w0 = *(const float4*)&sW[(lb + 0) * 4];
            float4 w1 = *(const float4*)&sW[(lb + 1) * 4];
            PB_FMA(w0, v0) PB_FMA(w1, v1)
        }
#undef PB_FMA
        pB[w][0][2 * lane] = h00; pB[w][0][2 * lane + 1] = h01;
        pB[w][1][2 * lane] = h10; pB[w][1][2 * lane + 1] = h11;
        pB[w][2][2 * lane] = h20; pB[w][2][2 * lane + 1] = h21;
    }
    __syncthreads();

    // (3a) reduce WA across waves
    if (t < DIN) {
#pragma unroll
        for (int k = 0; k < 3; ++k)
            sWA[k][t] = pB[0][k][t] + pB[1][k][t] + pB[2][k][t] + pB[3][k][t];
    }
    __syncthreads();

    // (3b) high_raw = WA @ S ; e = t&127, half hh of d-range. 8x8 named batches.
    {
        const int e = t & 127, hh = t >> 7;
        const float* Scol = S + e;
        float g0 = 0.f, g1 = 0.f, g2 = 0.f;
        for (int g = 0; g < 8; ++g) {
            const int db = hh * 64 + g * 8;
            float s0 = Scol[(db + 0) * DOUT];
            float s1 = Scol[(db + 1) * DOUT];
            float s2 = Scol[(db + 2) * DOUT];
            float s3 = Scol[(db + 3) * DOUT];
            float s4 = Scol[(db + 4) * DOUT];
            float s5 = Scol[(db + 5) * DOUT];
            float s6 = Scol[(db + 6) * DOUT];
            float s7 = Scol[(db + 7) * DOUT];
#define HB_FMA(J, SV) \
            g0 = fmaf(sWA[0][db + J], SV, g0); \
            g1 = fmaf(sWA[1][db + J], SV, g1); \
            g2 = fmaf(sWA[2][db + J], SV, g2);
            HB_FMA(0, s0) HB_FMA(1, s1) HB_FMA(2, s2) HB_FMA(3, s3)
            HB_FMA(4, s4) HB_FMA(5, s5) HB_FMA(6, s6) HB_FMA(7, s7)
#undef HB_FMA
        }
        pB[hh][0][e] = g0; pB[hh][1][e] = g1; pB[hh][2][e] = g2;
    }
    __syncthreads();

    // (3c) combine halves + squash (norm over k per (b,e)); write out on last iter
    if (t < DIN) {
        float g0 = pB[0][0][t] + pB[1][0][t];
        float g1 = pB[0][1][t] + pB[1][1][t];
        float g2 = pB[0][2][t] + pB[1][2][t];
        float sq = g0 * g0 + g1 * g1 + g2 * g2;
        float scale = sq / (1.f + sq) / sqrtf(sq + 1e-9f);
        g0 *= scale; g1 *= scale; g2 *= scale;
        if (iter == 2) {
            size_t o = (size_t)b * 3 * DOUT + t;
            out[o] = g0; out[o + DOUT] = g1; out[o + 2 * DOUT] = g2;
        } else {
            sH[0][t] = g0; sH[1][t] = g1; sH[2][t] = g2;
        }
    }
    if (iter == 2) return;   // uniform exit
    __syncthreads();

    // (4a) hS = high @ S^T ; d = t&127, half hh of e-range. 8x8 named batches.
    {
        const int d = t & 127, hh = t >> 7;
        const float* STcol = ST + d;
        float s0a = 0.f, s1a = 0.f, s2a = 0.f;
        for (int g = 0; g < 8; ++g) {
            const int eb = hh * 64 + g * 8;
            float s0 = STcol[(eb + 0) * DIN];
            float s1 = STcol[(eb + 1) * DIN];
            float s2 = STcol[(eb + 2) * DIN];
            float s3 = STcol[(eb + 3) * DIN];
            float s4 = STcol[(eb + 4) * DIN];
            float s5 = STcol[(eb + 5) * DIN];
            float s6 = STcol[(eb + 6) * DIN];
            float s7 = STcol[(eb + 7) * DIN];
#define HS_FMA(J, SV) \
            s0a = fmaf(sH[0][eb + J], SV, s0a); \
            s1a = fmaf(sH[1][eb + J], SV, s1a); \
            s2a = fmaf(sH[2][eb + J], SV, s2a);
            HS_FMA(0, s0) HS_FMA(1, s1) HS_FMA(2, s2) HS_FMA(3, s3)
            HS_FMA(4, s4) HS_FMA(5, s5) HS_FMA(6, s6) HS_FMA(7, s7)
#undef HS_FMA
        }
        pB[hh][0][d] = s0a; pB[hh][1][d] = s1a; pB[hh][2][d] = s2a;
    }
    __syncthreads();

    if (t < DIN) {
#pragma unroll
        for (int k = 0; k < 3; ++k)
            sHS[k][t] = pB[0][k][t] + pB[1][k][t];
    }
    __syncthreads();

    // (5) B_delta partials: thread = l reads its 512B A-row; 4 groups of
    //     8-deep named float4 batches.
    if (t < SEQ) {
        const float* row = Ab + (size_t)t * DIN;
        float d0 = 0.f, d1 = 0.f, d2 = 0.f;
        for (int g = 0; g < 4; ++g) {
            const int jb = g * 8;
            float4 u0 = *(const float4*)&row[4 * (jb + 0)];
            float4 u1 = *(const float4*)&row[4 * (jb + 1)];
            float4 u2 = *(const float4*)&row[4 * (jb + 2)];
            float4 u3 = *(const float4*)&row[4 * (jb + 3)];
            float4 u4 = *(const float4*)&row[4 * (jb + 4)];
            float4 u5 = *(const float4*)&row[4 * (jb + 5)];
            float4 u6 = *(const float4*)&row[4 * (jb + 6)];
            float4 u7 = *(const float4*)&row[4 * (jb + 7)];
#define PC_FMA(J, U) { \
            float4 x0 = *(const float4*)&sHS[0][4 * (jb + J)]; \
            float4 x1 = *(const float4*)&sHS[1][4 * (jb + J)]; \
            float4 x2 = *(const float4*)&sHS[2][4 * (jb + J)]; \
            d0 += x0.x * U.x + x0.y * U.y + x0.z * U.z + x0.w * U.w; \
            d1 += x1.x * U.x + x1.y * U.y + x1.z * U.z + x1.w * U.w; \
            d2 += x2.x * U.x + x2.y * U.y + x2.z * U.z + x2.w * U.w; }
            PC_FMA(0, u0) PC_FMA(1, u1) PC_FMA(2, u2) PC_FMA(3, u3)
            PC_FMA(4, u4) PC_FMA(5, u5) PC_FMA(6, u6) PC_FMA(7, u7)
#undef PC_FMA
        }
        float* pp = part + (size_t)b * PSTR;
        pp[t] = d0;
        pp[SEQ + t] = d1;
        pp[2 * SEQ + t] = d2;
    }
}

// ---- K3: column-sum part[1024][PSTR] -> accN[600]; 150 blocks x 4 cols ----
__global__ __launch_bounds__(256) void k_reduce(const float* __restrict__ part,
                                                float* __restrict__ accN) {
    __shared__ float sP[4][4];
    const int t = threadIdx.x, lane = t & 63, w = t >> 6;
    const int c4 = blockIdx.x * 4;
    float4 v0 = *(const float4*)&part[(size_t)(t + 256 * 0) * PSTR + c4];
    float4 v1 = *(const float4*)&part[(size_t)(t + 256 * 1) * PSTR + c4];
    float4 v2 = *(const float4*)&part[(size_t)(t + 256 * 2) * PSTR + c4];
    float4 v3 = *(const float4*)&part[(size_t)(t + 256 * 3) * PSTR + c4];
    float sx = v0.x + v1.x + v2.x + v3.x;
    float sy = v0.y + v1.y + v2.y + v3.y;
    float sz = v0.z + v1.z + v2.z + v3.z;
    float sw = v0.w + v1.w + v2.w + v3.w;
#pragma unroll
    for (int off = 1; off < 64; off <<= 1) {
        sx += __shfl_xor(sx, off, 64);
        sy += __shfl_xor(sy, off, 64);
        sz += __shfl_xor(sz, off, 64);
        sw += __shfl_xor(sw, off, 64);
    }
    if (lane == 0) { sP[w][0] = sx; sP[w][1] = sy; sP[w][2] = sz; sP[w][3] = sw; }
    __syncthreads();
    if (t < 4)
        accN[c4 + t] = sP[0][t] + sP[1][t] + sP[2][t] + sP[3][t];
}

extern "C" void kernel_launch(void* const* d_in, const int* in_sizes, int n_in,
                              void* d_out, int out_size, void* d_ws, size_t ws_size,
                              hipStream_t stream) {
    const float* low_capsule = (const float*)d_in[0];   // [1024][200][128]
    const float* B_matrix    = (const float*)d_in[1];   // [1][3][200]
    const float* S_matrix    = (const float*)d_in[2];   // [128][128]
    const int*   seq_len     = (const int*)d_in[3];     // [1024]
    float* out = (float*)d_out;                         // [1024][3][128]

    float* ST   = (float*)d_ws;          // 16384
    float* acc0 = ST + 16384;            // 600 (+pad)
    float* acc1 = acc0 + 640;            // 600 (+pad)
    float* part = acc1 + 640;            // 1024 * PSTR

    k_transpose<<<64, 256, 0, stream>>>(S_matrix, ST);

    k_iter<<<BATCH, 256, 0, stream>>>(low_capsule, S_matrix, ST, B_matrix,
                                      seq_len, acc0, acc1, part, out, 0);
    k_reduce<<<150, 256, 0, stream>>>(part, acc0);
    k_iter<<<BATCH, 256, 0, stream>>>(low_capsule, S_matrix, ST, B_matrix,
                                      seq_len, acc0, acc1, part, out, 1);
    k_reduce<<<150, 256, 0, stream>>>(part, acc1);
    k_iter<<<BATCH, 256, 0, stream>>>(low_capsule, S_matrix, ST, B_matrix,
                                      seq_len, acc0, acc1, part, out, 2);
}